// Round 10
// baseline (573.335 us; speedup 1.0000x reference)
//
#include <hip/hip_runtime.h>
#include <hip/hip_bf16.h>
#include <stdint.h>

#define N_NODES 8192
#define D_IN 256
#define D_OUT 128
#define BKK 64
#define KSPLIT 4
#define KSTEPS (N_NODES / KSPLIT / BKK)  // 32

typedef __bf16 bf16x8 __attribute__((ext_vector_type(8)));
typedef __bf16 bf16x4 __attribute__((ext_vector_type(4)));
typedef float f32x4 __attribute__((ext_vector_type(4)));

// ---------------- K1: rowsum -> dinv, and A fp32 -> bf16 (single pass) ----------------
__global__ __launch_bounds__(256) void k_prep(const float* __restrict__ A,
                                              __bf16* __restrict__ Abf,
                                              float* __restrict__ dinv) {
  const int t = threadIdx.x;
  const int wv = t >> 6, l = t & 63;
  const int r = blockIdx.x * 4 + wv;
  const f32x4* row = (const f32x4*)(A + (size_t)r * N_NODES);  // 2048 x f32x4
  bf16x8* orow = (bf16x8*)(Abf + (size_t)r * N_NODES);         // 1024 x bf16x8
  float s = 0.f;
#pragma unroll
  for (int i = 0; i < 16; ++i) {
    const int c = i * 64 + l;  // bf16x8 chunk index; covers [0,1024)
    f32x4 v0 = __builtin_nontemporal_load(&row[2 * c]);
    f32x4 v1 = __builtin_nontemporal_load(&row[2 * c + 1]);
    s += ((v0[0] + v0[1]) + (v0[2] + v0[3])) + ((v1[0] + v1[1]) + (v1[2] + v1[3]));
    bf16x8 h;
    h[0] = (__bf16)v0[0]; h[1] = (__bf16)v0[1]; h[2] = (__bf16)v0[2]; h[3] = (__bf16)v0[3];
    h[4] = (__bf16)v1[0]; h[5] = (__bf16)v1[1]; h[6] = (__bf16)v1[2]; h[7] = (__bf16)v1[3];
    orow[c] = h;  // cacheable: K3 re-reads Abf
  }
#pragma unroll
  for (int off = 32; off > 0; off >>= 1) s += __shfl_down(s, off, 64);
  if (l == 0) dinv[r] = 1.0f / sqrtf(s + 1e-8f);
}

// ---------------- K2: fc = V@W + b ; yT[c][r] = bf16(dinv[r]*fc[r][c]) ----------------
#define VPAD 260
__global__ __launch_bounds__(256) void k_fc(const float* __restrict__ values,
                                            const float* __restrict__ W,
                                            const float* __restrict__ bias,
                                            const float* __restrict__ dinv,
                                            __bf16* __restrict__ yT) {
  __shared__ float vsm[32 * VPAD];  // ~33 KB
  const int t = threadIdx.x;
  const int rb = blockIdx.x * 32;
  {
    const float4* src = (const float4*)(values + (size_t)rb * D_IN);
#pragma unroll
    for (int i = 0; i < 8; ++i) {
      int f = t + i * 256;          // float4 index over [32][64]
      int r = f >> 6, kq = f & 63;
      *(float4*)(vsm + r * VPAD + kq * 4) = src[f];
    }
  }
  __syncthreads();
  const int tr = t >> 5, tc = t & 31;
  const int c0 = tc * 4;
  float accm[4][4] = {};
  const float* vr = vsm + (tr * 4) * VPAD;
#pragma unroll 4
  for (int k4 = 0; k4 < 64; ++k4) {
    f32x4 a[4];
    float4 wv[4];
#pragma unroll
    for (int i = 0; i < 4; ++i) a[i] = *(const f32x4*)(vr + i * VPAD + k4 * 4);
#pragma unroll
    for (int kk = 0; kk < 4; ++kk) wv[kk] = *(const float4*)(W + (size_t)(k4 * 4 + kk) * D_OUT + c0);
#pragma unroll
    for (int i = 0; i < 4; ++i) {
      accm[i][0] += a[i][0] * wv[0].x + a[i][1] * wv[1].x + a[i][2] * wv[2].x + a[i][3] * wv[3].x;
      accm[i][1] += a[i][0] * wv[0].y + a[i][1] * wv[1].y + a[i][2] * wv[2].y + a[i][3] * wv[3].y;
      accm[i][2] += a[i][0] * wv[0].z + a[i][1] * wv[1].z + a[i][2] * wv[2].z + a[i][3] * wv[3].z;
      accm[i][3] += a[i][0] * wv[0].w + a[i][1] * wv[1].w + a[i][2] * wv[2].w + a[i][3] * wv[3].w;
    }
  }
  const int rg = rb + tr * 4;
  float dv[4];
#pragma unroll
  for (int i = 0; i < 4; ++i) dv[i] = dinv[rg + i];
#pragma unroll
  for (int j = 0; j < 4; ++j) {
    const int c = c0 + j;
    const float bc = bias[c];
    bf16x4 p;
#pragma unroll
    for (int i = 0; i < 4; ++i) p[i] = (__bf16)((accm[i][j] + bc) * dv[i]);
    *(bf16x4*)(yT + (size_t)c * N_NODES + rg) = p;
  }
}

// ---------------- K3: partial[s] = A[:, ks] @ y[ks, :]  (MFMA bf16, K-split) ----------------
__device__ __forceinline__ void gload_lds16(const void* gp, void* lp) {
  __builtin_amdgcn_global_load_lds((const __attribute__((address_space(1))) void*)gp,
                                   (__attribute__((address_space(3))) void*)lp, 16, 0, 0);
}

// BM=32, BN=128, BK=64, 4 waves. 2-buffer distance-1 pipeline, counted vmcnt(5).
// LDS 40 KB/block -> 4 blocks/CU, KSPLIT=4 -> 1024 blocks.
__global__ __launch_bounds__(256) void k_gemm(const __bf16* __restrict__ Abf,
                                              const __bf16* __restrict__ yT,
                                              float* __restrict__ partial) {
  __shared__ __align__(16) char smA[2][32 * 128];    // 4 KB each
  __shared__ __align__(16) char smB[2][128 * 128];   // 16 KB each
  const int t = threadIdx.x;
  const int l = t & 63;
  const int w = t >> 6;
  const int mb = blockIdx.x * 32;
  const int k0 = blockIdx.y * (N_NODES / KSPLIT);
  float* pout = partial + (size_t)blockIdx.y * N_NODES * D_OUT;

  const int am = t >> 3, aseg = t & 7;
  const __bf16* agp = Abf + (size_t)(mb + am) * N_NODES + k0 + ((aseg ^ (am & 7)) * 8);
  const int bn_base = w * 8 + (l >> 3);
  const int bseg = l & 7;

  f32x4 acc00 = {}, acc01 = {}, acc10 = {}, acc11 = {};
  const int lr = l & 15;
  const int lg = l >> 4;

  int aoff[2][2], boff[2][2];
#pragma unroll
  for (int mf = 0; mf < 2; ++mf)
#pragma unroll
    for (int ks = 0; ks < 2; ++ks) {
      int m = mf * 16 + lr;
      int seg = ks * 4 + lg;
      aoff[mf][ks] = m * 128 + ((seg ^ (m & 7)) * 16);
      int n = w * 32 + mf * 16 + lr;
      boff[mf][ks] = n * 128 + ((seg ^ (n & 7)) * 16);
    }

  auto stage = [&](int kb, int buf) {
    gload_lds16(agp + kb, (void*)(&smA[buf][0] + w * 1024));
#pragma unroll
    for (int q = 0; q < 4; ++q) {
      int n = q * 32 + bn_base;
      const __bf16* gp = yT + (size_t)n * N_NODES + k0 + kb + ((bseg ^ (n & 7)) * 8);
      gload_lds16(gp, (void*)(&smB[buf][0] + q * 4096 + w * 1024));
    }
  };

  stage(0, 0);

  for (int t_i = 0; t_i < KSTEPS; ++t_i) {
    const int b = t_i & 1;
    if (t_i + 1 < KSTEPS) {
      stage((t_i + 1) * BKK, b ^ 1);  // issue next tile's 5 loads (other buffer)
      asm volatile("s_waitcnt vmcnt(5)" ::: "memory");  // tile t_i landed; t_i+1 in flight
    } else {
      asm volatile("s_waitcnt vmcnt(0)" ::: "memory");
    }
    __builtin_amdgcn_s_barrier();

    bf16x8 af0a = *(const bf16x8*)(&smA[b][0] + aoff[0][0]);
    bf16x8 af1a = *(const bf16x8*)(&smA[b][0] + aoff[1][0]);
    bf16x8 bq0a = *(const bf16x8*)(&smB[b][0] + boff[0][0]);
    bf16x8 bq1a = *(const bf16x8*)(&smB[b][0] + boff[1][0]);
    bf16x8 af0b = *(const bf16x8*)(&smA[b][0] + aoff[0][1]);
    bf16x8 af1b = *(const bf16x8*)(&smA[b][0] + aoff[1][1]);
    bf16x8 bq0b = *(const bf16x8*)(&smB[b][0] + boff[0][1]);
    bf16x8 bq1b = *(const bf16x8*)(&smB[b][0] + boff[1][1]);
    asm volatile("s_waitcnt lgkmcnt(0)" ::: "memory");
    __builtin_amdgcn_sched_barrier(0);
    __builtin_amdgcn_s_barrier();

    acc00 = __builtin_amdgcn_mfma_f32_16x16x32_bf16(af0a, bq0a, acc00, 0, 0, 0);
    acc01 = __builtin_amdgcn_mfma_f32_16x16x32_bf16(af0a, bq1a, acc01, 0, 0, 0);
    acc10 = __builtin_amdgcn_mfma_f32_16x16x32_bf16(af1a, bq0a, acc10, 0, 0, 0);
    acc11 = __builtin_amdgcn_mfma_f32_16x16x32_bf16(af1a, bq1a, acc11, 0, 0, 0);
    acc00 = __builtin_amdgcn_mfma_f32_16x16x32_bf16(af0b, bq0b, acc00, 0, 0, 0);
    acc01 = __builtin_amdgcn_mfma_f32_16x16x32_bf16(af0b, bq1b, acc01, 0, 0, 0);
    acc10 = __builtin_amdgcn_mfma_f32_16x16x32_bf16(af1b, bq0b, acc10, 0, 0, 0);
    acc11 = __builtin_amdgcn_mfma_f32_16x16x32_bf16(af1b, bq1b, acc11, 0, 0, 0);
  }

#pragma unroll
  for (int mf = 0; mf < 2; ++mf) {
#pragma unroll
    for (int nf = 0; nf < 2; ++nf) {
      f32x4 a = (mf == 0) ? ((nf == 0) ? acc00 : acc01) : ((nf == 0) ? acc10 : acc11);
      const int col = w * 32 + nf * 16 + lr;
      const int rowb = mb + mf * 16 + lg * 4;
#pragma unroll
      for (int v2 = 0; v2 < 4; ++v2) {
        pout[(size_t)(rowb + v2) * D_OUT + col] = a[v2];
      }
    }
  }
}

// ---------------- K4: out = dinv ⊙ (p0 + p1 + p2 + p3) ----------------
__global__ __launch_bounds__(256) void k_finish(const float* __restrict__ partial,
                                                const float* __restrict__ dinv,
                                                float* __restrict__ out) {
  const int i = blockIdx.x * 256 + threadIdx.x;  // float4 index
  const size_t S = (size_t)N_NODES * D_OUT / 4;
  const f32x4* p = (const f32x4*)partial;
  f32x4 a = (p[i] + p[i + S]) + (p[i + 2 * S] + p[i + 3 * S]);
  const float dv = dinv[i >> 5];  // 32 float4 per row of 128
  f32x4* o = (f32x4*)out;
  o[i] = a * dv;
}

extern "C" void kernel_launch(void* const* d_in, const int* in_sizes, int n_in,
                              void* d_out, int out_size, void* d_ws, size_t ws_size,
                              hipStream_t stream) {
  const float* values = (const float*)d_in[0];
  const float* A = (const float*)d_in[1];
  const float* W = (const float*)d_in[2];
  const float* bias = (const float*)d_in[3];
  float* out = (float*)d_out;

  char* ws = (char*)d_ws;
  float* dinv = (float*)ws;                       // 32 KB
  __bf16* yT = (__bf16*)(ws + (64 << 10));        // 2 MB   [128][8192]
  float* partial = (float*)(ws + (4 << 20));      // 16 MB  [4][8192][128]
  __bf16* Abf = (__bf16*)(ws + (32 << 20));       // 128 MB [8192][8192]

  // MEASUREMENT ROUND: run the identical pipeline TWICE (all kernels idempotent).
  // K_total = dur2 - dur1(441); F_fixed = 2*441 - dur2. Same output, same work every call.
#pragma unroll
  for (int rep = 0; rep < 2; ++rep) {
    k_prep<<<N_NODES / 4, 256, 0, stream>>>(A, Abf, dinv);
    k_fc<<<N_NODES / 32, 256, 0, stream>>>(values, W, bias, dinv, yT);
    k_gemm<<<dim3(N_NODES / 32, KSPLIT), 256, 0, stream>>>(Abf, yT, partial);
    k_finish<<<N_NODES * D_OUT / 4 / 256, 256, 0, stream>>>(partial, dinv, out);
  }
}

// Round 11
// 440.197 us; speedup vs baseline: 1.3025x; 1.3025x over previous
//
#include <hip/hip_runtime.h>
#include <hip/hip_bf16.h>
#include <stdint.h>

#define N_NODES 8192
#define D_IN 256
#define D_OUT 128
#define BKK 64
#define KSPLIT 4
#define KSTEPS (N_NODES / KSPLIT / BKK)  // 32

typedef __bf16 bf16x8 __attribute__((ext_vector_type(8)));
typedef __bf16 bf16x4 __attribute__((ext_vector_type(4)));
typedef float f32x4 __attribute__((ext_vector_type(4)));

// ---------------- K1: rowsum -> dinv, and A fp32 -> bf16 (single pass) ----------------
// One WAVE per row (4 rows/block): no LDS, no barrier. BW-bound at ~384 MB.
__global__ __launch_bounds__(256) void k_prep(const float* __restrict__ A,
                                              __bf16* __restrict__ Abf,
                                              float* __restrict__ dinv) {
  const int t = threadIdx.x;
  const int wv = t >> 6, l = t & 63;
  const int r = blockIdx.x * 4 + wv;
  const f32x4* row = (const f32x4*)(A + (size_t)r * N_NODES);  // 2048 x f32x4
  bf16x8* orow = (bf16x8*)(Abf + (size_t)r * N_NODES);         // 1024 x bf16x8
  float s = 0.f;
#pragma unroll
  for (int i = 0; i < 16; ++i) {
    const int c = i * 64 + l;  // bf16x8 chunk index; covers [0,1024)
    f32x4 v0 = __builtin_nontemporal_load(&row[2 * c]);
    f32x4 v1 = __builtin_nontemporal_load(&row[2 * c + 1]);
    s += ((v0[0] + v0[1]) + (v0[2] + v0[3])) + ((v1[0] + v1[1]) + (v1[2] + v1[3]));
    bf16x8 h;
    h[0] = (__bf16)v0[0]; h[1] = (__bf16)v0[1]; h[2] = (__bf16)v0[2]; h[3] = (__bf16)v0[3];
    h[4] = (__bf16)v1[0]; h[5] = (__bf16)v1[1]; h[6] = (__bf16)v1[2]; h[7] = (__bf16)v1[3];
    orow[c] = h;  // cacheable: K3 re-reads Abf
  }
#pragma unroll
  for (int off = 32; off > 0; off >>= 1) s += __shfl_down(s, off, 64);
  if (l == 0) dinv[r] = 1.0f / sqrtf(s + 1e-8f);
}

// ---------------- K2: fc = V@W + b ; yT[c][r] = bf16(dinv[r]*fc[r][c]) ----------------
#define VPAD 260
__global__ __launch_bounds__(256) void k_fc(const float* __restrict__ values,
                                            const float* __restrict__ W,
                                            const float* __restrict__ bias,
                                            const float* __restrict__ dinv,
                                            __bf16* __restrict__ yT) {
  __shared__ float vsm[32 * VPAD];  // ~33 KB
  const int t = threadIdx.x;
  const int rb = blockIdx.x * 32;
  {
    const float4* src = (const float4*)(values + (size_t)rb * D_IN);
#pragma unroll
    for (int i = 0; i < 8; ++i) {
      int f = t + i * 256;          // float4 index over [32][64]
      int r = f >> 6, kq = f & 63;
      *(float4*)(vsm + r * VPAD + kq * 4) = src[f];
    }
  }
  __syncthreads();
  const int tr = t >> 5, tc = t & 31;
  const int c0 = tc * 4;
  float accm[4][4] = {};
  const float* vr = vsm + (tr * 4) * VPAD;
#pragma unroll 4
  for (int k4 = 0; k4 < 64; ++k4) {
    f32x4 a[4];
    float4 wv[4];
#pragma unroll
    for (int i = 0; i < 4; ++i) a[i] = *(const f32x4*)(vr + i * VPAD + k4 * 4);
#pragma unroll
    for (int kk = 0; kk < 4; ++kk) wv[kk] = *(const float4*)(W + (size_t)(k4 * 4 + kk) * D_OUT + c0);
#pragma unroll
    for (int i = 0; i < 4; ++i) {
      accm[i][0] += a[i][0] * wv[0].x + a[i][1] * wv[1].x + a[i][2] * wv[2].x + a[i][3] * wv[3].x;
      accm[i][1] += a[i][0] * wv[0].y + a[i][1] * wv[1].y + a[i][2] * wv[2].y + a[i][3] * wv[3].y;
      accm[i][2] += a[i][0] * wv[0].z + a[i][1] * wv[1].z + a[i][2] * wv[2].z + a[i][3] * wv[3].z;
      accm[i][3] += a[i][0] * wv[0].w + a[i][1] * wv[1].w + a[i][2] * wv[2].w + a[i][3] * wv[3].w;
    }
  }
  const int rg = rb + tr * 4;
  float dv[4];
#pragma unroll
  for (int i = 0; i < 4; ++i) dv[i] = dinv[rg + i];
#pragma unroll
  for (int j = 0; j < 4; ++j) {
    const int c = c0 + j;
    const float bc = bias[c];
    bf16x4 p;
#pragma unroll
    for (int i = 0; i < 4; ++i) p[i] = (__bf16)((accm[i][j] + bc) * dv[i]);
    *(bf16x4*)(yT + (size_t)c * N_NODES + rg) = p;
  }
}

// ---------------- K3: partial[s] = A[:, ks] @ y[ks, :]  (MFMA bf16, K-split) ----------------
__device__ __forceinline__ void gload_lds16(const void* gp, void* lp) {
  __builtin_amdgcn_global_load_lds((const __attribute__((address_space(1))) void*)gp,
                                   (__attribute__((address_space(3))) void*)lp, 16, 0, 0);
}

// BM=32, BN=128, BK=64, 4 waves. 2-buffer distance-1 pipeline, counted vmcnt(5).
// LDS 40 KB/block -> 4 blocks/CU, KSPLIT=4 -> 1024 blocks.
__global__ __launch_bounds__(256) void k_gemm(const __bf16* __restrict__ Abf,
                                              const __bf16* __restrict__ yT,
                                              float* __restrict__ partial) {
  __shared__ __align__(16) char smA[2][32 * 128];    // 4 KB each
  __shared__ __align__(16) char smB[2][128 * 128];   // 16 KB each
  const int t = threadIdx.x;
  const int l = t & 63;
  const int w = t >> 6;
  const int mb = blockIdx.x * 32;
  const int k0 = blockIdx.y * (N_NODES / KSPLIT);
  float* pout = partial + (size_t)blockIdx.y * N_NODES * D_OUT;

  const int am = t >> 3, aseg = t & 7;
  const __bf16* agp = Abf + (size_t)(mb + am) * N_NODES + k0 + ((aseg ^ (am & 7)) * 8);
  const int bn_base = w * 8 + (l >> 3);
  const int bseg = l & 7;

  f32x4 acc00 = {}, acc01 = {}, acc10 = {}, acc11 = {};
  const int lr = l & 15;
  const int lg = l >> 4;

  int aoff[2][2], boff[2][2];
#pragma unroll
  for (int mf = 0; mf < 2; ++mf)
#pragma unroll
    for (int ks = 0; ks < 2; ++ks) {
      int m = mf * 16 + lr;
      int seg = ks * 4 + lg;
      aoff[mf][ks] = m * 128 + ((seg ^ (m & 7)) * 16);
      int n = w * 32 + mf * 16 + lr;
      boff[mf][ks] = n * 128 + ((seg ^ (n & 7)) * 16);
    }

  auto stage = [&](int kb, int buf) {
    gload_lds16(agp + kb, (void*)(&smA[buf][0] + w * 1024));
#pragma unroll
    for (int q = 0; q < 4; ++q) {
      int n = q * 32 + bn_base;
      const __bf16* gp = yT + (size_t)n * N_NODES + k0 + kb + ((bseg ^ (n & 7)) * 8);
      gload_lds16(gp, (void*)(&smB[buf][0] + q * 4096 + w * 1024));
    }
  };

  stage(0, 0);

  for (int t_i = 0; t_i < KSTEPS; ++t_i) {
    const int b = t_i & 1;
    if (t_i + 1 < KSTEPS) {
      stage((t_i + 1) * BKK, b ^ 1);  // issue next tile's 5 loads (other buffer)
      asm volatile("s_waitcnt vmcnt(5)" ::: "memory");  // tile t_i landed; t_i+1 in flight
    } else {
      asm volatile("s_waitcnt vmcnt(0)" ::: "memory");
    }
    __builtin_amdgcn_s_barrier();

    bf16x8 af0a = *(const bf16x8*)(&smA[b][0] + aoff[0][0]);
    bf16x8 af1a = *(const bf16x8*)(&smA[b][0] + aoff[1][0]);
    bf16x8 bq0a = *(const bf16x8*)(&smB[b][0] + boff[0][0]);
    bf16x8 bq1a = *(const bf16x8*)(&smB[b][0] + boff[1][0]);
    bf16x8 af0b = *(const bf16x8*)(&smA[b][0] + aoff[0][1]);
    bf16x8 af1b = *(const bf16x8*)(&smA[b][0] + aoff[1][1]);
    bf16x8 bq0b = *(const bf16x8*)(&smB[b][0] + boff[0][1]);
    bf16x8 bq1b = *(const bf16x8*)(&smB[b][0] + boff[1][1]);
    asm volatile("s_waitcnt lgkmcnt(0)" ::: "memory");
    __builtin_amdgcn_sched_barrier(0);
    __builtin_amdgcn_s_barrier();

    acc00 = __builtin_amdgcn_mfma_f32_16x16x32_bf16(af0a, bq0a, acc00, 0, 0, 0);
    acc01 = __builtin_amdgcn_mfma_f32_16x16x32_bf16(af0a, bq1a, acc01, 0, 0, 0);
    acc10 = __builtin_amdgcn_mfma_f32_16x16x32_bf16(af1a, bq0a, acc10, 0, 0, 0);
    acc11 = __builtin_amdgcn_mfma_f32_16x16x32_bf16(af1a, bq1a, acc11, 0, 0, 0);
    acc00 = __builtin_amdgcn_mfma_f32_16x16x32_bf16(af0b, bq0b, acc00, 0, 0, 0);
    acc01 = __builtin_amdgcn_mfma_f32_16x16x32_bf16(af0b, bq1b, acc01, 0, 0, 0);
    acc10 = __builtin_amdgcn_mfma_f32_16x16x32_bf16(af1b, bq0b, acc10, 0, 0, 0);
    acc11 = __builtin_amdgcn_mfma_f32_16x16x32_bf16(af1b, bq1b, acc11, 0, 0, 0);
  }

#pragma unroll
  for (int mf = 0; mf < 2; ++mf) {
#pragma unroll
    for (int nf = 0; nf < 2; ++nf) {
      f32x4 a = (mf == 0) ? ((nf == 0) ? acc00 : acc01) : ((nf == 0) ? acc10 : acc11);
      const int col = w * 32 + nf * 16 + lr;
      const int rowb = mb + mf * 16 + lg * 4;
#pragma unroll
      for (int v2 = 0; v2 < 4; ++v2) {
        pout[(size_t)(rowb + v2) * D_OUT + col] = a[v2];
      }
    }
  }
}

// ---------------- K4: out = dinv ⊙ (p0 + p1 + p2 + p3) ----------------
__global__ __launch_bounds__(256) void k_finish(const float* __restrict__ partial,
                                                const float* __restrict__ dinv,
                                                float* __restrict__ out) {
  const int i = blockIdx.x * 256 + threadIdx.x;  // float4 index
  const size_t S = (size_t)N_NODES * D_OUT / 4;
  const f32x4* p = (const f32x4*)partial;
  f32x4 a = (p[i] + p[i + S]) + (p[i + 2 * S] + p[i + 3 * S]);
  const float dv = dinv[i >> 5];  // 32 float4 per row of 128
  f32x4* o = (f32x4*)out;
  o[i] = a * dv;
}

extern "C" void kernel_launch(void* const* d_in, const int* in_sizes, int n_in,
                              void* d_out, int out_size, void* d_ws, size_t ws_size,
                              hipStream_t stream) {
  const float* values = (const float*)d_in[0];
  const float* A = (const float*)d_in[1];
  const float* W = (const float*)d_in[2];
  const float* bias = (const float*)d_in[3];
  float* out = (float*)d_out;

  char* ws = (char*)d_ws;
  float* dinv = (float*)ws;                       // 32 KB
  __bf16* yT = (__bf16*)(ws + (64 << 10));        // 2 MB   [128][8192]
  float* partial = (float*)(ws + (4 << 20));      // 16 MB  [4][8192][128]
  __bf16* Abf = (__bf16*)(ws + (32 << 20));       // 128 MB [8192][8192]

  k_prep<<<N_NODES / 4, 256, 0, stream>>>(A, Abf, dinv);
  k_fc<<<N_NODES / 32, 256, 0, stream>>>(values, W, bias, dinv, yT);
  k_gemm<<<dim3(N_NODES / 32, KSPLIT), 256, 0, stream>>>(Abf, yT, partial);
  k_finish<<<N_NODES * D_OUT / 4 / 256, 256, 0, stream>>>(partial, dinv, out);
}